// Round 1
// baseline (321.186 us; speedup 1.0000x reference)
//
#include <hip/hip_runtime.h>
#include <hip/hip_bf16.h>

#define NFFT    1024
#define HOPSZ   256
#define XLEN    262144
#define PADLEN  (XLEN + NFFT)      // 263168, center padding 512 each side
#define NBATCH  16
#define NBINS2  1026               // 513 cos + 513 sin rows
#define FBIN    513
#define NFRAMES 1025
#define TOTOUT  ((size_t)NBATCH * FBIN * NFRAMES)   // elements per (real|imag) block

typedef short bf16x8 __attribute__((ext_vector_type(8)));
typedef float f32x4  __attribute__((ext_vector_type(4)));
typedef unsigned short u16x8 __attribute__((ext_vector_type(8)));
typedef unsigned short u16x4 __attribute__((ext_vector_type(4)));

__device__ __forceinline__ unsigned short f2bf(float f) {
  union { float f; unsigned u; } v; v.f = f;
  unsigned r = v.u + 0x7fffu + ((v.u >> 16) & 1u);   // round-to-nearest-even
  return (unsigned short)(r >> 16);
}

typedef __attribute__((address_space(1))) void void_g;
typedef __attribute__((address_space(3))) void void_l;
__device__ __forceinline__ void gload_lds16(const void* g, void* l) {
  __builtin_amdgcn_global_load_lds((void_g*)(g), (void_l*)(l), 16, 0, 0);
}

// ---- pack x -> bf16 with center padding, per batch PADLEN samples ----
__global__ __launch_bounds__(256) void pack_x_kernel(const float* __restrict__ x,
                                                     unsigned short* __restrict__ xp) {
  long long t = (long long)blockIdx.x * 256 + threadIdx.x;
  long long base = t * 8;
  if (base >= (long long)NBATCH * PADLEN) return;
  int b   = (int)(base / PADLEN);
  int pos = (int)(base % PADLEN);
  const float* xb = x + (long long)b * XLEN;
  u16x8 v;
#pragma unroll
  for (int j = 0; j < 8; ++j) {
    int xi = pos + j - (NFFT / 2);
    float f = ((unsigned)xi < (unsigned)XLEN) ? xb[xi] : 0.0f;
    v[j] = f2bf(f);
  }
  *reinterpret_cast<u16x8*>(xp + base) = v;
}

// ---- pack W -> bf16, row-major (1026 x 1024) ----
__global__ __launch_bounds__(256) void pack_w_kernel(const float* __restrict__ W,
                                                     unsigned short* __restrict__ Wb) {
  long long t = ((long long)blockIdx.x * 256 + threadIdx.x) * 4;
  if (t >= (long long)NBINS2 * NFFT) return;
  float4 f = *reinterpret_cast<const float4*>(W + t);
  u16x4 v;
  v[0] = f2bf(f.x); v[1] = f2bf(f.y); v[2] = f2bf(f.z); v[3] = f2bf(f.w);
  *reinterpret_cast<u16x4*>(Wb + t) = v;
}

// ---- main MFMA GEMM: bins(M) x frames(N), 128x128 tile, BK=64 ----
// covers bins 0..1023, frames 0..1023 (tails handled by stft_direct_kernel)
__global__ __launch_bounds__(256) void stft_mfma_kernel(const unsigned short* __restrict__ Xp,
                                                        const unsigned short* __restrict__ Wb,
                                                        float* __restrict__ out) {
  __shared__ unsigned short As[128 * 64];   // W tile: rows = bins
  __shared__ unsigned short Bs[128 * 64];   // x tile: rows = frames
  const int tid  = threadIdx.x;
  const int lane = tid & 63;
  const int w    = tid >> 6;
  const int wr   = w >> 1;          // wave's bin-half  (0/1)
  const int wc   = w & 1;           // wave's frame-half(0/1)
  const int bin0 = blockIdx.x * 128;
  const int fr0  = blockIdx.y * 128;
  const int b    = blockIdx.z;

  const unsigned short* xb = Xp + (size_t)b * PADLEN;

  f32x4 acc[4][4] = {};

  const int srow = lane >> 3;          // 0..7 row within 8-row chunk
  const int scol = (lane & 7) * 8;     // 0..56 col (elements)

  for (int kc = 0; kc < NFFT; kc += 64) {
#pragma unroll
    for (int j = 0; j < 4; ++j) {
      const int chunk = w * 4 + j;              // 0..15, wave-uniform
      const int row   = chunk * 8 + srow;       // 0..127
      gload_lds16(Wb + (size_t)(bin0 + row) * NFFT + kc + scol, &As[chunk * 512]);
      gload_lds16(xb + (size_t)(fr0 + row) * HOPSZ + kc + scol, &Bs[chunk * 512]);
    }
    __syncthreads();

#pragma unroll
    for (int ks = 0; ks < 2; ++ks) {
      const int kof = ks * 32 + (lane >> 4) * 8;
      const int r16 = lane & 15;
      bf16x8 af[4], bfr[4];
#pragma unroll
      for (int m = 0; m < 4; ++m)
        af[m] = *reinterpret_cast<const bf16x8*>(&As[(wr * 64 + m * 16 + r16) * 64 + kof]);
#pragma unroll
      for (int n = 0; n < 4; ++n)
        bfr[n] = *reinterpret_cast<const bf16x8*>(&Bs[(wc * 64 + n * 16 + r16) * 64 + kof]);
#pragma unroll
      for (int m = 0; m < 4; ++m)
#pragma unroll
        for (int n = 0; n < 4; ++n)
          acc[m][n] = __builtin_amdgcn_mfma_f32_16x16x32_bf16(af[m], bfr[n], acc[m][n], 0, 0, 0);
    }
    __syncthreads();
  }

  // epilogue: D row = bin (row=(lane>>4)*4+r), col = frame (col=lane&15)
  const int col   = lane & 15;
  const int rbase = (lane >> 4) * 4;
#pragma unroll
  for (int m = 0; m < 4; ++m) {
#pragma unroll
    for (int n = 0; n < 4; ++n) {
      const int frame = fr0 + wc * 64 + n * 16 + col;
#pragma unroll
      for (int r = 0; r < 4; ++r) {
        const int bin = bin0 + wr * 64 + m * 16 + rbase + r;
        size_t off;
        if (bin < FBIN) off = ((size_t)b * FBIN + bin) * NFRAMES + frame;
        else            off = TOTOUT + ((size_t)b * FBIN + (bin - FBIN)) * NFRAMES + frame;
        out[off] = acc[m][n][r];
      }
    }
  }
}

// ---- exact f32 direct kernel: edges + fallback ----
__global__ void stft_direct_kernel(const float* __restrict__ x, const float* __restrict__ W,
                                   float* __restrict__ out,
                                   int bin_lo, int nbins, int fr_lo, int nframes) {
  long long total = (long long)NBATCH * nbins * nframes;
  for (long long t = (long long)blockIdx.x * blockDim.x + threadIdx.x; t < total;
       t += (long long)gridDim.x * blockDim.x) {
    int fr = fr_lo + (int)(t % nframes);
    long long q = t / nframes;
    int bin = bin_lo + (int)(q % nbins);
    int b   = (int)(q / nbins);
    const float* xb = x + (long long)b * XLEN;
    const float* wrow = W + (long long)bin * NFFT;
    float s = 0.f;
    const int base = fr * HOPSZ - (NFFT / 2);
    for (int j = 0; j < NFFT; ++j) {
      int xi = base + j;
      float xv = ((unsigned)xi < (unsigned)XLEN) ? xb[xi] : 0.f;
      s = fmaf(xv, wrow[j], s);
    }
    size_t off;
    if (bin < FBIN) off = ((size_t)b * FBIN + bin) * NFRAMES + fr;
    else            off = TOTOUT + ((size_t)b * FBIN + (bin - FBIN)) * NFRAMES + fr;
    out[off] = s;
  }
}

extern "C" void kernel_launch(void* const* d_in, const int* in_sizes, int n_in,
                              void* d_out, int out_size, void* d_ws, size_t ws_size,
                              hipStream_t stream) {
  const float* x = (const float*)d_in[0];
  const float* W = (const float*)d_in[1];
  float* out = (float*)d_out;

  const size_t xp_bytes = (size_t)NBATCH * PADLEN * sizeof(unsigned short);
  const size_t wb_bytes = (size_t)NBINS2 * NFFT * sizeof(unsigned short);

  if (ws_size >= xp_bytes + wb_bytes) {
    unsigned short* xp = (unsigned short*)d_ws;
    unsigned short* wb = (unsigned short*)((char*)d_ws + xp_bytes);

    {
      long long threads = (long long)NBATCH * PADLEN / 8;
      pack_x_kernel<<<(int)((threads + 255) / 256), 256, 0, stream>>>(x, xp);
    }
    pack_w_kernel<<<(NBINS2 * NFFT / 4 + 255) / 256, 256, 0, stream>>>(W, wb);

    stft_mfma_kernel<<<dim3(8, 8, NBATCH), 256, 0, stream>>>(xp, wb, out);

    // frame 1024, all 1026 bins
    stft_direct_kernel<<<65, 256, 0, stream>>>(x, W, out, 0, NBINS2, NFRAMES - 1, 1);
    // kernel rows 1024..1025 (imag bins 511,512), frames 0..1023
    stft_direct_kernel<<<128, 256, 0, stream>>>(x, W, out, 1024, 2, 0, 1024);
  } else {
    // fallback: exact f32 for everything
    stft_direct_kernel<<<2048, 256, 0, stream>>>(x, W, out, 0, NBINS2, 0, NFRAMES);
  }
}

// Round 2
// 105.911 us; speedup vs baseline: 3.0326x; 3.0326x over previous
//
#include <hip/hip_runtime.h>
#include <hip/hip_bf16.h>

#define NFFT    1024
#define HOPSZ   256
#define XLEN    262144
#define PADLEN  (XLEN + NFFT)      // 263168, center padding 512 each side
#define NBATCH  16
#define NBINS2  1026               // 513 cos + 513 sin rows
#define FBIN    513
#define NFRAMES 1025
#define TOTOUT  ((size_t)NBATCH * FBIN * NFRAMES)   // elements per (real|imag) block

typedef short bf16x8 __attribute__((ext_vector_type(8)));
typedef float f32x4  __attribute__((ext_vector_type(4)));
typedef unsigned short u16x8 __attribute__((ext_vector_type(8)));
typedef unsigned short u16x4 __attribute__((ext_vector_type(4)));

__device__ __forceinline__ unsigned short f2bf(float f) {
  union { float f; unsigned u; } v; v.f = f;
  unsigned r = v.u + 0x7fffu + ((v.u >> 16) & 1u);   // round-to-nearest-even
  return (unsigned short)(r >> 16);
}

typedef __attribute__((address_space(1))) void void_g;
typedef __attribute__((address_space(3))) void void_l;
__device__ __forceinline__ void gload_lds16(const void* g, void* l) {
  __builtin_amdgcn_global_load_lds((void_g*)(g), (void_l*)(l), 16, 0, 0);
}

// ---- pack x -> bf16 with center padding, per batch PADLEN samples ----
__global__ __launch_bounds__(256) void pack_x_kernel(const float* __restrict__ x,
                                                     unsigned short* __restrict__ xp) {
  long long t = (long long)blockIdx.x * 256 + threadIdx.x;
  long long base = t * 8;
  if (base >= (long long)NBATCH * PADLEN) return;
  int b   = (int)(base / PADLEN);
  int pos = (int)(base % PADLEN);
  const float* xb = x + (long long)b * XLEN;
  u16x8 v;
#pragma unroll
  for (int j = 0; j < 8; ++j) {
    int xi = pos + j - (NFFT / 2);
    float f = ((unsigned)xi < (unsigned)XLEN) ? xb[xi] : 0.0f;
    v[j] = f2bf(f);
  }
  *reinterpret_cast<u16x8*>(xp + base) = v;
}

// ---- pack W -> bf16, row-major (1026 x 1024) ----
__global__ __launch_bounds__(256) void pack_w_kernel(const float* __restrict__ W,
                                                     unsigned short* __restrict__ Wb) {
  long long t = ((long long)blockIdx.x * 256 + threadIdx.x) * 4;
  if (t >= (long long)NBINS2 * NFFT) return;
  float4 f = *reinterpret_cast<const float4*>(W + t);
  u16x4 v;
  v[0] = f2bf(f.x); v[1] = f2bf(f.y); v[2] = f2bf(f.z); v[3] = f2bf(f.w);
  *reinterpret_cast<u16x4*>(Wb + t) = v;
}

// ---- main MFMA GEMM: bins(M) x frames(N), 128x128 tile, BK=64 ----
// 9x9 tile grid covers ALL bins (0..1025) and frames (0..1024).
// Out-of-range tile rows clamp their load address to row 0 (in-bounds garbage);
// the epilogue bounds-check discards those accumulator outputs.
__global__ __launch_bounds__(256) void stft_mfma_kernel(const unsigned short* __restrict__ Xp,
                                                        const unsigned short* __restrict__ Wb,
                                                        float* __restrict__ out) {
  __shared__ unsigned short As[128 * 64];   // W tile: rows = bins
  __shared__ unsigned short Bs[128 * 64];   // x tile: rows = frames
  const int tid  = threadIdx.x;
  const int lane = tid & 63;
  const int w    = tid >> 6;
  const int wr   = w >> 1;          // wave's bin-half  (0/1)
  const int wc   = w & 1;           // wave's frame-half(0/1)
  const int bin0 = blockIdx.x * 128;
  const int fr0  = blockIdx.y * 128;
  const int b    = blockIdx.z;

  const unsigned short* xb = Xp + (size_t)b * PADLEN;

  f32x4 acc[4][4] = {};

  const int srow = lane >> 3;          // 0..7 row within 8-row chunk
  const int scol = (lane & 7) * 8;     // 0..56 col (elements)

  for (int kc = 0; kc < NFFT; kc += 64) {
#pragma unroll
    for (int j = 0; j < 4; ++j) {
      const int chunk = w * 4 + j;              // 0..15, wave-uniform
      const int row   = chunk * 8 + srow;       // 0..127
      int arow = bin0 + row; if (arow >= NBINS2)  arow = 0;   // clamp, discarded later
      int brow = fr0  + row; if (brow >= NFRAMES) brow = 0;   // clamp, discarded later
      gload_lds16(Wb + (size_t)arow * NFFT + kc + scol, &As[chunk * 512]);
      gload_lds16(xb + (size_t)brow * HOPSZ + kc + scol, &Bs[chunk * 512]);
    }
    __syncthreads();

#pragma unroll
    for (int ks = 0; ks < 2; ++ks) {
      const int kof = ks * 32 + (lane >> 4) * 8;
      const int r16 = lane & 15;
      bf16x8 af[4], bfr[4];
#pragma unroll
      for (int m = 0; m < 4; ++m)
        af[m] = *reinterpret_cast<const bf16x8*>(&As[(wr * 64 + m * 16 + r16) * 64 + kof]);
#pragma unroll
      for (int n = 0; n < 4; ++n)
        bfr[n] = *reinterpret_cast<const bf16x8*>(&Bs[(wc * 64 + n * 16 + r16) * 64 + kof]);
#pragma unroll
      for (int m = 0; m < 4; ++m)
#pragma unroll
        for (int n = 0; n < 4; ++n)
          acc[m][n] = __builtin_amdgcn_mfma_f32_16x16x32_bf16(af[m], bfr[n], acc[m][n], 0, 0, 0);
    }
    __syncthreads();
  }

  // epilogue: D row = bin (row=(lane>>4)*4+r), col = frame (col=lane&15)
  const int col   = lane & 15;
  const int rbase = (lane >> 4) * 4;
#pragma unroll
  for (int m = 0; m < 4; ++m) {
#pragma unroll
    for (int n = 0; n < 4; ++n) {
      const int frame = fr0 + wc * 64 + n * 16 + col;
      if (frame >= NFRAMES) continue;
#pragma unroll
      for (int r = 0; r < 4; ++r) {
        const int bin = bin0 + wr * 64 + m * 16 + rbase + r;
        if (bin >= NBINS2) continue;
        size_t off;
        if (bin < FBIN) off = ((size_t)b * FBIN + bin) * NFRAMES + frame;
        else            off = TOTOUT + ((size_t)b * FBIN + (bin - FBIN)) * NFRAMES + frame;
        out[off] = acc[m][n][r];
      }
    }
  }
}

// ---- exact f32 direct kernel: fallback only ----
__global__ void stft_direct_kernel(const float* __restrict__ x, const float* __restrict__ W,
                                   float* __restrict__ out,
                                   int bin_lo, int nbins, int fr_lo, int nframes) {
  long long total = (long long)NBATCH * nbins * nframes;
  for (long long t = (long long)blockIdx.x * blockDim.x + threadIdx.x; t < total;
       t += (long long)gridDim.x * blockDim.x) {
    int fr = fr_lo + (int)(t % nframes);
    long long q = t / nframes;
    int bin = bin_lo + (int)(q % nbins);
    int b   = (int)(q / nbins);
    const float* xb = x + (long long)b * XLEN;
    const float* wrow = W + (long long)bin * NFFT;
    float s = 0.f;
    const int base = fr * HOPSZ - (NFFT / 2);
    for (int j = 0; j < NFFT; ++j) {
      int xi = base + j;
      float xv = ((unsigned)xi < (unsigned)XLEN) ? xb[xi] : 0.f;
      s = fmaf(xv, wrow[j], s);
    }
    size_t off;
    if (bin < FBIN) off = ((size_t)b * FBIN + bin) * NFRAMES + fr;
    else            off = TOTOUT + ((size_t)b * FBIN + (bin - FBIN)) * NFRAMES + fr;
    out[off] = s;
  }
}

extern "C" void kernel_launch(void* const* d_in, const int* in_sizes, int n_in,
                              void* d_out, int out_size, void* d_ws, size_t ws_size,
                              hipStream_t stream) {
  const float* x = (const float*)d_in[0];
  const float* W = (const float*)d_in[1];
  float* out = (float*)d_out;

  const size_t xp_bytes = (size_t)NBATCH * PADLEN * sizeof(unsigned short);
  const size_t wb_bytes = (size_t)NBINS2 * NFFT * sizeof(unsigned short);

  if (ws_size >= xp_bytes + wb_bytes) {
    unsigned short* xp = (unsigned short*)d_ws;
    unsigned short* wb = (unsigned short*)((char*)d_ws + xp_bytes);

    {
      long long threads = (long long)NBATCH * PADLEN / 8;
      pack_x_kernel<<<(int)((threads + 255) / 256), 256, 0, stream>>>(x, xp);
    }
    pack_w_kernel<<<(NBINS2 * NFFT / 4 + 255) / 256, 256, 0, stream>>>(W, wb);

    // 9x9 tile grid: covers bins 0..1151 (clamped/masked) x frames 0..1151
    stft_mfma_kernel<<<dim3(9, 9, NBATCH), 256, 0, stream>>>(xp, wb, out);
  } else {
    // fallback: exact f32 for everything
    stft_direct_kernel<<<2048, 256, 0, stream>>>(x, W, out, 0, NBINS2, 0, NFRAMES);
  }
}

// Round 3
// 89.310 us; speedup vs baseline: 3.5963x; 1.1859x over previous
//
#include <hip/hip_runtime.h>
#include <hip/hip_bf16.h>

#define NFFT    1024
#define HOPSZ   256
#define XLEN    262144
#define PADLEN  (XLEN + NFFT)      // 263168
#define NBATCH  16
#define NBINS2  1026               // 513 cos + 513 sin rows
#define FBIN    513
#define NFRAMES 1025
#define NGF     (NBATCH * NFRAMES) // 16400 global frames
#define TOTOUT  ((size_t)NBATCH * FBIN * NFRAMES)

// 8-phase-style GEMM geometry
#define BM 128
#define BN 256
#define KT 64
#define NKT 16                     // K = 1024
#define MT_TILES 9                 // ceil(1026/128)
#define NT_TILES 65                // ceil(16400/256)
#define NWG (MT_TILES * NT_TILES)  // 585
#define ABUF 8192                  // A elems per buffer (128x64)
#define BBUF 16384                 // B elems per buffer (256x64)
#define BUFE (ABUF + BBUF)         // 24576 elems = 49152 B per buffer
#define BUFB (BUFE * 2)            // bytes

typedef short bf16x8 __attribute__((ext_vector_type(8)));
typedef float f32x4  __attribute__((ext_vector_type(4)));
typedef unsigned short u16x8 __attribute__((ext_vector_type(8)));
typedef unsigned short u16x4 __attribute__((ext_vector_type(4)));

__device__ __forceinline__ unsigned short f2bf(float f) {
  union { float f; unsigned u; } v; v.f = f;
  unsigned r = v.u + 0x7fffu + ((v.u >> 16) & 1u);   // RNE
  return (unsigned short)(r >> 16);
}

typedef __attribute__((address_space(1))) void void_g;
typedef __attribute__((address_space(3))) void void_l;
__device__ __forceinline__ void gload_lds16(const void* g, void* l) {
  __builtin_amdgcn_global_load_lds((void_g*)(g), (void_l*)(l), 16, 0, 0);
}

// ---- pack x -> bf16 with center padding ----
__global__ __launch_bounds__(256) void pack_x_kernel(const float* __restrict__ x,
                                                     unsigned short* __restrict__ xp) {
  long long t = (long long)blockIdx.x * 256 + threadIdx.x;
  long long base = t * 8;
  if (base >= (long long)NBATCH * PADLEN) return;
  int b   = (int)(base / PADLEN);
  int pos = (int)(base % PADLEN);
  const float* xb = x + (long long)b * XLEN;
  u16x8 v;
#pragma unroll
  for (int j = 0; j < 8; ++j) {
    int xi = pos + j - (NFFT / 2);
    float f = ((unsigned)xi < (unsigned)XLEN) ? xb[xi] : 0.0f;
    v[j] = f2bf(f);
  }
  *reinterpret_cast<u16x8*>(xp + base) = v;
}

// ---- pack W -> bf16 ----
__global__ __launch_bounds__(256) void pack_w_kernel(const float* __restrict__ W,
                                                     unsigned short* __restrict__ Wb) {
  long long t = ((long long)blockIdx.x * 256 + threadIdx.x) * 4;
  if (t >= (long long)NBINS2 * NFFT) return;
  float4 f = *reinterpret_cast<const float4*>(W + t);
  u16x4 v;
  v[0] = f2bf(f.x); v[1] = f2bf(f.y); v[2] = f2bf(f.z); v[3] = f2bf(f.w);
  *reinterpret_cast<u16x4*>(Wb + t) = v;
}

// ---- 8-wave phase-split GEMM, 3-buffer LDS ring, counted vmcnt, T2 swizzle ----
// M = bins (1026, padded 1152), N = global frames (16400, padded 16640), K = 1024.
__global__ __launch_bounds__(512, 2) void stft_mfma8_kernel(const unsigned short* __restrict__ Xp,
                                                            const unsigned short* __restrict__ Wb,
                                                            float* __restrict__ out) {
  extern __shared__ unsigned short lds[];   // 3 * 48 KiB = 144 KiB
  const int tid = threadIdx.x;
  const int l   = tid & 63;
  const int w   = tid >> 6;        // 0..7
  const int wr  = w >> 2;          // 0..1  (M half)
  const int wc  = w & 3;           // 0..3  (N quarter)
  const int r16 = l & 15, hi = l >> 4;

  // bijective XCD swizzle (585 = 8*73 + 1): consecutive wgid share the A panel
  const int idx  = blockIdx.x;
  const int xcd  = idx & 7;
  const int wgid = (xcd < 1 ? xcd * 74 : 74 + (xcd - 1) * 73) + (idx >> 3);
  const int mt   = wgid / NT_TILES;
  const int nt   = wgid - mt * NT_TILES;
  const int bin0 = mt * BM;
  const int gf0  = nt * BN;

  // ---- staging pointers (pre-swizzled global source: slot ls holds col16 ls^lr) ----
  const int lr = l >> 3;   // row-within-8  (row & 7 == lr for every staged row)
  const int ls = l & 7;    // 16B slot
  const int cswz = ((ls ^ lr) << 3);   // elems

  int ra0 = (w * 2 + 0) * 8 + lr;
  int ra1 = (w * 2 + 1) * 8 + lr;
  int ga0 = bin0 + ra0; if (ga0 >= NBINS2) ga0 = 0;
  int ga1 = bin0 + ra1; if (ga1 >= NBINS2) ga1 = 0;
  const unsigned short* aptr0 = Wb + (size_t)ga0 * NFFT + cswz;
  const unsigned short* aptr1 = Wb + (size_t)ga1 * NFFT + cswz;

  const unsigned short* bptr0; const unsigned short* bptr1;
  const unsigned short* bptr2; const unsigned short* bptr3;
  {
    int rb, gf, bb, fr;
#define BSET(J, P) \
    rb = (w * 4 + (J)) * 8 + lr; gf = gf0 + rb; if (gf >= NGF) gf = 0; \
    bb = gf / NFRAMES; fr = gf - bb * NFRAMES; \
    P = Xp + (size_t)bb * PADLEN + (size_t)fr * HOPSZ + cswz;
    BSET(0, bptr0) BSET(1, bptr1) BSET(2, bptr2) BSET(3, bptr3)
#undef BSET
  }

#define STAGE_A(SB) do { \
    gload_lds16(aptr0, lds + (SB) * BUFE + (w * 2 + 0) * 512); \
    gload_lds16(aptr1, lds + (SB) * BUFE + (w * 2 + 1) * 512); \
    aptr0 += KT; aptr1 += KT; } while (0)
#define STAGE_B01(SB) do { \
    gload_lds16(bptr0, lds + (SB) * BUFE + ABUF + (w * 4 + 0) * 512); \
    gload_lds16(bptr1, lds + (SB) * BUFE + ABUF + (w * 4 + 1) * 512); \
    bptr0 += KT; bptr1 += KT; } while (0)
#define STAGE_B23(SB) do { \
    gload_lds16(bptr2, lds + (SB) * BUFE + ABUF + (w * 4 + 2) * 512); \
    gload_lds16(bptr3, lds + (SB) * BUFE + ABUF + (w * 4 + 3) * 512); \
    bptr2 += KT; bptr3 += KT; } while (0)

  // ---- fragment read offsets (T2 XOR-swizzle on the 16B slot index) ----
  const int aRow = (wr * 64 + r16) * 128;            // byte, A region
  const int bRow = ABUF * 2 + (wc * 64 + r16) * 128; // byte, B region
  const int swz  = (r16 & 7) << 4;
  const int c0   = (hi * 16) ^ swz;                  // ks = 0
  const int c1   = (64 + hi * 16) ^ swz;             // ks = 1

  f32x4 acc[4][4] = {};

  // ---- prologue: stage tiles 0,1 ----
  STAGE_A(0); STAGE_B01(0); STAGE_B23(0);
  STAGE_A(1); STAGE_B01(1); STAGE_B23(1);
  asm volatile("s_waitcnt vmcnt(6)" ::: "memory");   // tile 0 landed, tile 1 in flight
  __builtin_amdgcn_s_barrier();
  __builtin_amdgcn_sched_barrier(0);

  int cur = 0;
  for (int t = 0; t < NKT; ++t) {
    const char* base = (const char*)lds + cur * BUFB;
    int sb = cur + 2; if (sb >= 3) sb -= 3;
    const bool stage = (t < NKT - 2);

#define LDA(M, C) (*reinterpret_cast<const bf16x8*>(base + aRow + (M) * 2048 + (C)))
#define LDB(N, C) (*reinterpret_cast<const bf16x8*>(base + bRow + (N) * 2048 + (C)))

    bf16x8 Bf[4], A0, A1;

    // P0: ks0, m0-1
    Bf[0] = LDB(0, c0); Bf[1] = LDB(1, c0); Bf[2] = LDB(2, c0); Bf[3] = LDB(3, c0);
    A0 = LDA(0, c0); A1 = LDA(1, c0);
    if (stage) STAGE_A(sb);
    __builtin_amdgcn_s_setprio(1);
#pragma unroll
    for (int n = 0; n < 4; ++n) {
      acc[0][n] = __builtin_amdgcn_mfma_f32_16x16x32_bf16(A0, Bf[n], acc[0][n], 0, 0, 0);
      acc[1][n] = __builtin_amdgcn_mfma_f32_16x16x32_bf16(A1, Bf[n], acc[1][n], 0, 0, 0);
    }
    __builtin_amdgcn_s_setprio(0);
    __builtin_amdgcn_s_barrier();

    // P1: ks0, m2-3
    A0 = LDA(2, c0); A1 = LDA(3, c0);
    if (stage) STAGE_B01(sb);
    __builtin_amdgcn_s_setprio(1);
#pragma unroll
    for (int n = 0; n < 4; ++n) {
      acc[2][n] = __builtin_amdgcn_mfma_f32_16x16x32_bf16(A0, Bf[n], acc[2][n], 0, 0, 0);
      acc[3][n] = __builtin_amdgcn_mfma_f32_16x16x32_bf16(A1, Bf[n], acc[3][n], 0, 0, 0);
    }
    __builtin_amdgcn_s_setprio(0);
    __builtin_amdgcn_s_barrier();

    // P2: ks1, m0-1
    Bf[0] = LDB(0, c1); Bf[1] = LDB(1, c1); Bf[2] = LDB(2, c1); Bf[3] = LDB(3, c1);
    A0 = LDA(0, c1); A1 = LDA(1, c1);
    if (stage) STAGE_B23(sb);
    __builtin_amdgcn_s_setprio(1);
#pragma unroll
    for (int n = 0; n < 4; ++n) {
      acc[0][n] = __builtin_amdgcn_mfma_f32_16x16x32_bf16(A0, Bf[n], acc[0][n], 0, 0, 0);
      acc[1][n] = __builtin_amdgcn_mfma_f32_16x16x32_bf16(A1, Bf[n], acc[1][n], 0, 0, 0);
    }
    __builtin_amdgcn_s_setprio(0);
    __builtin_amdgcn_s_barrier();

    // P3: ks1, m2-3  + iter-boundary counted wait
    A0 = LDA(2, c1); A1 = LDA(3, c1);
    __builtin_amdgcn_s_setprio(1);
#pragma unroll
    for (int n = 0; n < 4; ++n) {
      acc[2][n] = __builtin_amdgcn_mfma_f32_16x16x32_bf16(A0, Bf[n], acc[2][n], 0, 0, 0);
      acc[3][n] = __builtin_amdgcn_mfma_f32_16x16x32_bf16(A1, Bf[n], acc[3][n], 0, 0, 0);
    }
    __builtin_amdgcn_s_setprio(0);
    if (t < NKT - 2)       asm volatile("s_waitcnt vmcnt(6)" ::: "memory");
    else if (t == NKT - 2) asm volatile("s_waitcnt vmcnt(0)" ::: "memory");
    __builtin_amdgcn_s_barrier();
    __builtin_amdgcn_sched_barrier(0);

    cur = cur + 1; if (cur >= 3) cur = 0;
#undef LDA
#undef LDB
  }

  // ---- epilogue: D row = bin, col = global frame ----
  const int col   = l & 15;
  const int rbase = (l >> 4) * 4;
#pragma unroll
  for (int m = 0; m < 4; ++m) {
#pragma unroll
    for (int n = 0; n < 4; ++n) {
      const int gf = gf0 + wc * 64 + n * 16 + col;
      if (gf >= NGF) continue;
      const int bb = gf / NFRAMES;
      const int fr = gf - bb * NFRAMES;
#pragma unroll
      for (int r = 0; r < 4; ++r) {
        const int bin = bin0 + wr * 64 + m * 16 + rbase + r;
        if (bin >= NBINS2) continue;
        size_t off;
        if (bin < FBIN) off = ((size_t)bb * FBIN + bin) * NFRAMES + fr;
        else            off = TOTOUT + ((size_t)bb * FBIN + (bin - FBIN)) * NFRAMES + fr;
        out[off] = acc[m][n][r];
      }
    }
  }
}

// ---- exact f32 direct kernel: fallback only ----
__global__ void stft_direct_kernel(const float* __restrict__ x, const float* __restrict__ W,
                                   float* __restrict__ out,
                                   int bin_lo, int nbins, int fr_lo, int nframes) {
  long long total = (long long)NBATCH * nbins * nframes;
  for (long long t = (long long)blockIdx.x * blockDim.x + threadIdx.x; t < total;
       t += (long long)gridDim.x * blockDim.x) {
    int fr = fr_lo + (int)(t % nframes);
    long long q = t / nframes;
    int bin = bin_lo + (int)(q % nbins);
    int b   = (int)(q / nbins);
    const float* xb = x + (long long)b * XLEN;
    const float* wrow = W + (long long)bin * NFFT;
    float s = 0.f;
    const int base = fr * HOPSZ - (NFFT / 2);
    for (int j = 0; j < NFFT; ++j) {
      int xi = base + j;
      float xv = ((unsigned)xi < (unsigned)XLEN) ? xb[xi] : 0.f;
      s = fmaf(xv, wrow[j], s);
    }
    size_t off;
    if (bin < FBIN) off = ((size_t)b * FBIN + bin) * NFRAMES + fr;
    else            off = TOTOUT + ((size_t)b * FBIN + (bin - FBIN)) * NFRAMES + fr;
    out[off] = s;
  }
}

extern "C" void kernel_launch(void* const* d_in, const int* in_sizes, int n_in,
                              void* d_out, int out_size, void* d_ws, size_t ws_size,
                              hipStream_t stream) {
  const float* x = (const float*)d_in[0];
  const float* W = (const float*)d_in[1];
  float* out = (float*)d_out;

  const size_t xp_bytes = (size_t)NBATCH * PADLEN * sizeof(unsigned short);
  const size_t wb_bytes = (size_t)NBINS2 * NFFT * sizeof(unsigned short);

  if (ws_size >= xp_bytes + wb_bytes) {
    unsigned short* xp = (unsigned short*)d_ws;
    unsigned short* wb = (unsigned short*)((char*)d_ws + xp_bytes);

    {
      long long threads = (long long)NBATCH * PADLEN / 8;
      pack_x_kernel<<<(int)((threads + 255) / 256), 256, 0, stream>>>(x, xp);
    }
    pack_w_kernel<<<(NBINS2 * NFFT / 4 + 255) / 256, 256, 0, stream>>>(W, wb);

    stft_mfma8_kernel<<<NWG, 512, 3 * BUFB, stream>>>(xp, wb, out);
  } else {
    stft_direct_kernel<<<2048, 256, 0, stream>>>(x, W, out, 0, NBINS2, 0, NFRAMES);
  }
}

// Round 4
// 89.040 us; speedup vs baseline: 3.6072x; 1.0030x over previous
//
#include <hip/hip_runtime.h>
#include <hip/hip_bf16.h>

#define NFFT    1024
#define HOPSZ   256
#define XLEN    262144
#define PADLEN  (XLEN + NFFT)      // 263168
#define NBATCH  16
#define NBINS2  1026               // 513 cos + 513 sin rows
#define FBIN    513
#define NFRAMES 1025
#define NGF     (NBATCH * NFRAMES) // 16400 global frames
#define TOTOUT  ((size_t)NBATCH * FBIN * NFRAMES)

// GEMM geometry
#define BM 128
#define BN 256
#define KT 64
#define NKT 16                     // K = 1024
#define MT_TILES 9
#define NT_TILES 65
#define NWG (MT_TILES * NT_TILES)  // 585
#define ABUF 8192                  // A elems per buffer (128x64)
#define BBUF 16384                 // B elems per buffer (256x64)
#define BUFE (ABUF + BBUF)         // 24576 elems
#define BUFB (BUFE * 2)            // 49152 bytes

typedef short bf16x8 __attribute__((ext_vector_type(8)));
typedef float f32x4  __attribute__((ext_vector_type(4)));
typedef unsigned short u16x8 __attribute__((ext_vector_type(8)));
typedef unsigned short u16x4 __attribute__((ext_vector_type(4)));

__device__ __forceinline__ unsigned short f2bf(float f) {
  union { float f; unsigned u; } v; v.f = f;
  unsigned r = v.u + 0x7fffu + ((v.u >> 16) & 1u);   // RNE
  return (unsigned short)(r >> 16);
}

typedef __attribute__((address_space(1))) void void_g;
typedef __attribute__((address_space(3))) void void_l;
__device__ __forceinline__ void gload_lds16(const void* g, void* l) {
  __builtin_amdgcn_global_load_lds((void_g*)(g), (void_l*)(l), 16, 0, 0);
}

// ---- pack x -> bf16 with center padding ----
__global__ __launch_bounds__(256) void pack_x_kernel(const float* __restrict__ x,
                                                     unsigned short* __restrict__ xp) {
  long long t = (long long)blockIdx.x * 256 + threadIdx.x;
  long long base = t * 8;
  if (base >= (long long)NBATCH * PADLEN) return;
  int b   = (int)(base / PADLEN);
  int pos = (int)(base % PADLEN);
  const float* xb = x + (long long)b * XLEN;
  u16x8 v;
#pragma unroll
  for (int j = 0; j < 8; ++j) {
    int xi = pos + j - (NFFT / 2);
    float f = ((unsigned)xi < (unsigned)XLEN) ? xb[xi] : 0.0f;
    v[j] = f2bf(f);
  }
  *reinterpret_cast<u16x8*>(xp + base) = v;
}

// ---- pack W -> bf16 ----
__global__ __launch_bounds__(256) void pack_w_kernel(const float* __restrict__ W,
                                                     unsigned short* __restrict__ Wb) {
  long long t = ((long long)blockIdx.x * 256 + threadIdx.x) * 4;
  if (t >= (long long)NBINS2 * NFFT) return;
  float4 f = *reinterpret_cast<const float4*>(W + t);
  u16x4 v;
  v[0] = f2bf(f.x); v[1] = f2bf(f.y); v[2] = f2bf(f.z); v[3] = f2bf(f.w);
  *reinterpret_cast<u16x4*>(Wb + t) = v;
}

// ---- 8-wave phase-split GEMM, 3-ring LDS, counted vmcnt/lgkmcnt, T2 swizzle,
//      register-double-buffered fragments (reads one phase ahead) ----
__global__ __launch_bounds__(512, 2) void stft_mfma8_kernel(const unsigned short* __restrict__ Xp,
                                                            const unsigned short* __restrict__ Wb,
                                                            float* __restrict__ out) {
  extern __shared__ unsigned short lds[];   // 3 * 48 KiB
  const int tid = threadIdx.x;
  const int l   = tid & 63;
  const int w   = tid >> 6;        // 0..7
  const int wr  = w >> 2;          // M half
  const int wc  = w & 3;           // N quarter
  const int r16 = l & 15, hi = l >> 4;

  // bijective XCD swizzle (585 = 8*73 + 1)
  const int idx  = blockIdx.x;
  const int xcd  = idx & 7;
  const int wgid = (xcd < 1 ? xcd * 74 : 74 + (xcd - 1) * 73) + (idx >> 3);
  const int mt   = wgid / NT_TILES;
  const int nt   = wgid - mt * NT_TILES;
  const int bin0 = mt * BM;
  const int gf0  = nt * BN;

  // staging pointers (pre-swizzled global source)
  const int lr = l >> 3;
  const int ls = l & 7;
  const int cswz = ((ls ^ lr) << 3);

  int ra0 = (w * 2 + 0) * 8 + lr;
  int ra1 = (w * 2 + 1) * 8 + lr;
  int ga0 = bin0 + ra0; if (ga0 >= NBINS2) ga0 = 0;
  int ga1 = bin0 + ra1; if (ga1 >= NBINS2) ga1 = 0;
  const unsigned short* aptr0 = Wb + (size_t)ga0 * NFFT + cswz;
  const unsigned short* aptr1 = Wb + (size_t)ga1 * NFFT + cswz;

  const unsigned short* bptr0; const unsigned short* bptr1;
  const unsigned short* bptr2; const unsigned short* bptr3;
  {
    int rb, gf, bb, fr;
#define BSET(J, P) \
    rb = (w * 4 + (J)) * 8 + lr; gf = gf0 + rb; if (gf >= NGF) gf = 0; \
    bb = gf / NFRAMES; fr = gf - bb * NFRAMES; \
    P = Xp + (size_t)bb * PADLEN + (size_t)fr * HOPSZ + cswz;
    BSET(0, bptr0) BSET(1, bptr1) BSET(2, bptr2) BSET(3, bptr3)
#undef BSET
  }

#define STAGE_A(SB) do { \
    gload_lds16(aptr0, lds + (SB) * BUFE + (w * 2 + 0) * 512); \
    gload_lds16(aptr1, lds + (SB) * BUFE + (w * 2 + 1) * 512); \
    aptr0 += KT; aptr1 += KT; } while (0)
#define STAGE_B01(SB) do { \
    gload_lds16(bptr0, lds + (SB) * BUFE + ABUF + (w * 4 + 0) * 512); \
    gload_lds16(bptr1, lds + (SB) * BUFE + ABUF + (w * 4 + 1) * 512); \
    bptr0 += KT; bptr1 += KT; } while (0)
#define STAGE_B23(SB) do { \
    gload_lds16(bptr2, lds + (SB) * BUFE + ABUF + (w * 4 + 2) * 512); \
    gload_lds16(bptr3, lds + (SB) * BUFE + ABUF + (w * 4 + 3) * 512); \
    bptr2 += KT; bptr3 += KT; } while (0)

  // fragment read offsets (T2 XOR-swizzle on the 16B slot)
  const int aRow = (wr * 64 + r16) * 128;
  const int bRow = ABUF * 2 + (wc * 64 + r16) * 128;
  const int swz  = (r16 & 7) << 4;
  const int c0   = (hi * 16) ^ swz;
  const int c1   = (64 + hi * 16) ^ swz;

#define LDAF(BASE, M, C) (*reinterpret_cast<const bf16x8*>((BASE) + aRow + (M) * 2048 + (C)))
#define LDBF(BASE, N, C) (*reinterpret_cast<const bf16x8*>((BASE) + bRow + (N) * 2048 + (C)))

  f32x4 acc[4][4] = {};
  bf16x8 Ac0[4], Ac1[4], Bc0[4], Bc1[4];

  // ---- prologue: stage tiles 0,1; read-ahead tile 0 ks0 frags ----
  STAGE_A(0); STAGE_B01(0); STAGE_B23(0);
  STAGE_A(1); STAGE_B01(1); STAGE_B23(1);
  asm volatile("s_waitcnt vmcnt(6)" ::: "memory");   // tile 0 landed
  __builtin_amdgcn_s_barrier();
  __builtin_amdgcn_sched_barrier(0);
  {
    const char* base0 = (const char*)lds;
#pragma unroll
    for (int n = 0; n < 4; ++n) Bc0[n] = LDBF(base0, n, c0);
#pragma unroll
    for (int m = 0; m < 4; ++m) Ac0[m] = LDAF(base0, m, c0);
  }

  int cur = 0;
  for (int t = 0; t < NKT; ++t) {
    const char* base = (const char*)lds + cur * BUFB;
    int nxt = cur + 1; if (nxt >= 3) nxt = 0;
    int sb  = cur + 2; if (sb  >= 3) sb  -= 3;
    const bool stage = (t < NKT - 2);

    // ---- P0: MFMA m0-1 x ks0 (frags read last iter / prologue) ----
    if (stage) STAGE_A(sb);
    asm volatile("s_waitcnt lgkmcnt(2)" ::: "memory");  // B0-3,A0,A1 @ks0 done
    __builtin_amdgcn_sched_barrier(0);
    __builtin_amdgcn_s_setprio(1);
#pragma unroll
    for (int n = 0; n < 4; ++n) {
      acc[0][n] = __builtin_amdgcn_mfma_f32_16x16x32_bf16(Ac0[0], Bc0[n], acc[0][n], 0, 0, 0);
      acc[1][n] = __builtin_amdgcn_mfma_f32_16x16x32_bf16(Ac0[1], Bc0[n], acc[1][n], 0, 0, 0);
    }
    __builtin_amdgcn_s_setprio(0);
    __builtin_amdgcn_s_barrier();

    // ---- P1: issue all ks1 reads; MFMA m2-3 x ks0 ----
#pragma unroll
    for (int n = 0; n < 4; ++n) Bc1[n] = LDBF(base, n, c1);
#pragma unroll
    for (int m = 0; m < 4; ++m) Ac1[m] = LDAF(base, m, c1);
    if (stage) STAGE_B01(sb);
    asm volatile("s_waitcnt lgkmcnt(8)" ::: "memory");  // A2,A3 @ks0 done
    __builtin_amdgcn_sched_barrier(0);
    __builtin_amdgcn_s_setprio(1);
#pragma unroll
    for (int n = 0; n < 4; ++n) {
      acc[2][n] = __builtin_amdgcn_mfma_f32_16x16x32_bf16(Ac0[2], Bc0[n], acc[2][n], 0, 0, 0);
      acc[3][n] = __builtin_amdgcn_mfma_f32_16x16x32_bf16(Ac0[3], Bc0[n], acc[3][n], 0, 0, 0);
    }
    __builtin_amdgcn_s_setprio(0);
    __builtin_amdgcn_s_barrier();

    // ---- P2: MFMA m0-1 x ks1 ----
    if (stage) STAGE_B23(sb);
    asm volatile("s_waitcnt lgkmcnt(2)" ::: "memory");  // B0-3,A0,A1 @ks1 done
    __builtin_amdgcn_sched_barrier(0);
    __builtin_amdgcn_s_setprio(1);
#pragma unroll
    for (int n = 0; n < 4; ++n) {
      acc[0][n] = __builtin_amdgcn_mfma_f32_16x16x32_bf16(Ac1[0], Bc1[n], acc[0][n], 0, 0, 0);
      acc[1][n] = __builtin_amdgcn_mfma_f32_16x16x32_bf16(Ac1[1], Bc1[n], acc[1][n], 0, 0, 0);
    }
    __builtin_amdgcn_s_setprio(0);
    __builtin_amdgcn_s_barrier();

    // ---- P3: drain DS; counted vmcnt; barrier; read-ahead next tile ks0;
    //          MFMA m2-3 x ks1 ----
    asm volatile("s_waitcnt lgkmcnt(0)" ::: "memory");  // A2,A3 @ks1 done
    __builtin_amdgcn_sched_barrier(0);
    if (t < NKT - 2)       asm volatile("s_waitcnt vmcnt(6)" ::: "memory");
    else if (t == NKT - 2) asm volatile("s_waitcnt vmcnt(0)" ::: "memory");
    __builtin_amdgcn_s_barrier();      // all waves: buf t+1 staged, buf t reads drained
    __builtin_amdgcn_sched_barrier(0);
    if (t < NKT - 1) {
      const char* nb = (const char*)lds + nxt * BUFB;
#pragma unroll
      for (int n = 0; n < 4; ++n) Bc0[n] = LDBF(nb, n, c0);
#pragma unroll
      for (int m = 0; m < 4; ++m) Ac0[m] = LDAF(nb, m, c0);
    }
    __builtin_amdgcn_s_setprio(1);
#pragma unroll
    for (int n = 0; n < 4; ++n) {
      acc[2][n] = __builtin_amdgcn_mfma_f32_16x16x32_bf16(Ac1[2], Bc1[n], acc[2][n], 0, 0, 0);
      acc[3][n] = __builtin_amdgcn_mfma_f32_16x16x32_bf16(Ac1[3], Bc1[n], acc[3][n], 0, 0, 0);
    }
    __builtin_amdgcn_s_setprio(0);
    __builtin_amdgcn_s_barrier();

    cur = nxt;
  }

  // ---- epilogue ----
  const int col   = l & 15;
  const int rbase = (l >> 4) * 4;
#pragma unroll
  for (int m = 0; m < 4; ++m) {
#pragma unroll
    for (int n = 0; n < 4; ++n) {
      const int gf = gf0 + wc * 64 + n * 16 + col;
      if (gf >= NGF) continue;
      const int bb = gf / NFRAMES;
      const int fr = gf - bb * NFRAMES;
#pragma unroll
      for (int r = 0; r < 4; ++r) {
        const int bin = bin0 + wr * 64 + m * 16 + rbase + r;
        if (bin >= NBINS2) continue;
        size_t off;
        if (bin < FBIN) off = ((size_t)bb * FBIN + bin) * NFRAMES + fr;
        else            off = TOTOUT + ((size_t)bb * FBIN + (bin - FBIN)) * NFRAMES + fr;
        out[off] = acc[m][n][r];
      }
    }
  }
#undef LDAF
#undef LDBF
#undef STAGE_A
#undef STAGE_B01
#undef STAGE_B23
}

// ---- exact f32 direct kernel: fallback only ----
__global__ void stft_direct_kernel(const float* __restrict__ x, const float* __restrict__ W,
                                   float* __restrict__ out,
                                   int bin_lo, int nbins, int fr_lo, int nframes) {
  long long total = (long long)NBATCH * nbins * nframes;
  for (long long t = (long long)blockIdx.x * blockDim.x + threadIdx.x; t < total;
       t += (long long)gridDim.x * blockDim.x) {
    int fr = fr_lo + (int)(t % nframes);
    long long q = t / nframes;
    int bin = bin_lo + (int)(q % nbins);
    int b   = (int)(q / nbins);
    const float* xb = x + (long long)b * XLEN;
    const float* wrow = W + (long long)bin * NFFT;
    float s = 0.f;
    const int base = fr * HOPSZ - (NFFT / 2);
    for (int j = 0; j < NFFT; ++j) {
      int xi = base + j;
      float xv = ((unsigned)xi < (unsigned)XLEN) ? xb[xi] : 0.f;
      s = fmaf(xv, wrow[j], s);
    }
    size_t off;
    if (bin < FBIN) off = ((size_t)b * FBIN + bin) * NFRAMES + fr;
    else            off = TOTOUT + ((size_t)b * FBIN + (bin - FBIN)) * NFRAMES + fr;
    out[off] = s;
  }
}

extern "C" void kernel_launch(void* const* d_in, const int* in_sizes, int n_in,
                              void* d_out, int out_size, void* d_ws, size_t ws_size,
                              hipStream_t stream) {
  const float* x = (const float*)d_in[0];
  const float* W = (const float*)d_in[1];
  float* out = (float*)d_out;

  const size_t xp_bytes = (size_t)NBATCH * PADLEN * sizeof(unsigned short);
  const size_t wb_bytes = (size_t)NBINS2 * NFFT * sizeof(unsigned short);

  if (ws_size >= xp_bytes + wb_bytes) {
    unsigned short* xp = (unsigned short*)d_ws;
    unsigned short* wb = (unsigned short*)((char*)d_ws + xp_bytes);

    {
      long long threads = (long long)NBATCH * PADLEN / 8;
      pack_x_kernel<<<(int)((threads + 255) / 256), 256, 0, stream>>>(x, xp);
    }
    pack_w_kernel<<<(NBINS2 * NFFT / 4 + 255) / 256, 256, 0, stream>>>(W, wb);

    stft_mfma8_kernel<<<NWG, 512, 3 * BUFB, stream>>>(xp, wb, out);
  } else {
    stft_direct_kernel<<<2048, 256, 0, stream>>>(x, W, out, 0, NBINS2, 0, NFRAMES);
  }
}